// Round 1
// baseline (804.265 us; speedup 1.0000x reference)
//
#include <hip/hip_runtime.h>

// SimpleGraphConv (RGCN-mean): out[n] = bias + sum_r mean_{e: dst=n, type=r} (x[src] @ W[r])
//
// Decomposition:
//   counts[r][n]  = #edges of type r into n          (int atomics, once)
//   inv[r][n]     = counts>0 ? 1/counts : 0
//   per relation r:
//     T = x @ W[r]                                   (f32 vector GEMM, LDS-tiled)
//     for e with type[e]==r: out[dst[e]] += T[src[e]] * inv[r][dst[e]]   (f32 atomics)

#define C128 128

__global__ __launch_bounds__(256) void init_out_kernel(float* __restrict__ out,
                                                       const float* __restrict__ bias,
                                                       int total) {
    int i = blockIdx.x * 256 + threadIdx.x;
    if (i < total) out[i] = bias[i & (C128 - 1)];
}

__global__ __launch_bounds__(256) void count_kernel(const int* __restrict__ ei,
                                                    const int* __restrict__ et,
                                                    unsigned int* __restrict__ cnt,
                                                    int n_edges, int n_nodes) {
    int e = blockIdx.x * 256 + threadIdx.x;
    if (e < n_edges) {
        int r = et[e];
        int dst = ei[n_edges + e];
        atomicAdd(&cnt[(size_t)r * n_nodes + dst], 1u);
    }
}

__global__ __launch_bounds__(256) void inv_kernel(const unsigned int* __restrict__ cnt,
                                                  float* __restrict__ inv, int total) {
    int i = blockIdx.x * 256 + threadIdx.x;
    if (i < total) {
        unsigned int c = cnt[i];
        inv[i] = c ? (1.0f / (float)c) : 0.0f;
    }
}

// T[row][col] = sum_k x[row][k] * W[k][col]   (one relation's W, 128x128)
// Block: 256 threads, 32-row tile, full 128 cols. 4x4 micro-tile per thread.
__global__ __launch_bounds__(256) void gemm_kernel(const float* __restrict__ x,
                                                   const float* __restrict__ W,
                                                   float* __restrict__ T,
                                                   int n_nodes) {
    __shared__ float sW[C128][C128];   // 64 KB
    __shared__ float sA[32][C128];     // 16 KB
    for (int i = threadIdx.x; i < C128 * C128; i += 256)
        sW[i >> 7][i & 127] = W[i];
    int row0 = blockIdx.x * 32;
    for (int i = threadIdx.x; i < 32 * C128; i += 256) {
        int rr = i >> 7, cc = i & 127;
        int gr = row0 + rr;
        sA[rr][cc] = (gr < n_nodes) ? x[(size_t)gr * C128 + cc] : 0.0f;
    }
    __syncthreads();

    int cg = (threadIdx.x & 31) << 2;  // col base (0..124)
    int rg = (threadIdx.x >> 5) << 2;  // row base within tile (0..28)

    float acc[4][4];
#pragma unroll
    for (int i = 0; i < 4; ++i)
#pragma unroll
        for (int j = 0; j < 4; ++j) acc[i][j] = 0.0f;

    for (int k = 0; k < C128; k += 4) {
        float4 a[4], w[4];
#pragma unroll
        for (int i = 0; i < 4; ++i)
            a[i] = *reinterpret_cast<const float4*>(&sA[rg + i][k]);
#pragma unroll
        for (int kk = 0; kk < 4; ++kk)
            w[kk] = *reinterpret_cast<const float4*>(&sW[k + kk][cg]);
#pragma unroll
        for (int i = 0; i < 4; ++i) {
            const float* av = reinterpret_cast<const float*>(&a[i]);
#pragma unroll
            for (int kk = 0; kk < 4; ++kk) {
                acc[i][0] = fmaf(av[kk], w[kk].x, acc[i][0]);
                acc[i][1] = fmaf(av[kk], w[kk].y, acc[i][1]);
                acc[i][2] = fmaf(av[kk], w[kk].z, acc[i][2]);
                acc[i][3] = fmaf(av[kk], w[kk].w, acc[i][3]);
            }
        }
    }

#pragma unroll
    for (int i = 0; i < 4; ++i) {
        int gr = row0 + rg + i;
        if (gr < n_nodes) {
            float4 v = make_float4(acc[i][0], acc[i][1], acc[i][2], acc[i][3]);
            *reinterpret_cast<float4*>(&T[(size_t)gr * C128 + cg]) = v;
        }
    }
}

// One wave per edge; lanes cover 128 channels (2 each). Skip non-matching relation.
__global__ __launch_bounds__(256) void scatter_kernel(const float* __restrict__ T,
                                                      const int* __restrict__ ei,
                                                      const int* __restrict__ et,
                                                      const float* __restrict__ inv,
                                                      float* __restrict__ out,
                                                      int n_edges, int n_nodes, int rel) {
    int e = blockIdx.x * 4 + (threadIdx.x >> 6);
    if (e >= n_edges) return;
    if (et[e] != rel) return;
    int lane = threadIdx.x & 63;
    int src = ei[e];
    int dst = ei[n_edges + e];
    float s = inv[(size_t)rel * n_nodes + dst];
    float v0 = T[(size_t)src * C128 + lane] * s;
    float v1 = T[(size_t)src * C128 + 64 + lane] * s;
    atomicAdd(&out[(size_t)dst * C128 + lane], v0);
    atomicAdd(&out[(size_t)dst * C128 + 64 + lane], v1);
}

extern "C" void kernel_launch(void* const* d_in, const int* in_sizes, int n_in,
                              void* d_out, int out_size, void* d_ws, size_t ws_size,
                              hipStream_t stream) {
    const float* x    = (const float*)d_in[0];
    const int*   ei   = (const int*)d_in[1];   // [2][E] (src row, dst row)
    const int*   et   = (const int*)d_in[2];   // [E]
    const float* W    = (const float*)d_in[3]; // [R][128][128]
    const float* bias = (const float*)d_in[4]; // [128]
    float* out = (float*)d_out;

    const int n_nodes = in_sizes[0] / C128;
    const int n_edges = in_sizes[2];
    const int n_rel   = in_sizes[3] / (C128 * C128);

    // workspace: T [N][128] f32 | cnt [R][N] u32 | inv [R][N] f32  (~28.8 MB)
    float* T = (float*)d_ws;
    unsigned int* cnt = (unsigned int*)(T + (size_t)n_nodes * C128);
    float* inv = (float*)(cnt + (size_t)n_rel * n_nodes);

    hipMemsetAsync(cnt, 0, (size_t)n_rel * n_nodes * sizeof(unsigned int), stream);

    count_kernel<<<(n_edges + 255) / 256, 256, 0, stream>>>(ei, et, cnt, n_edges, n_nodes);

    int rn = n_rel * n_nodes;
    inv_kernel<<<(rn + 255) / 256, 256, 0, stream>>>(cnt, inv, rn);

    int total_out = n_nodes * C128;
    init_out_kernel<<<(total_out + 255) / 256, 256, 0, stream>>>(out, bias, total_out);

    for (int r = 0; r < n_rel; ++r) {
        gemm_kernel<<<(n_nodes + 31) / 32, 256, 0, stream>>>(
            x, W + (size_t)r * C128 * C128, T, n_nodes);
        scatter_kernel<<<(n_edges + 3) / 4, 256, 0, stream>>>(
            T, ei, et, inv, out, n_edges, n_nodes, r);
    }
}

// Round 2
// 276.963 us; speedup vs baseline: 2.9039x; 2.9039x over previous
//
#include <hip/hip_runtime.h>
#include <hip/hip_bf16.h>

// SimpleGraphConv (RGCN-mean), aggregate-first formulation:
//   out[n] = bias + sum_r ( mean_{e: dst=n, type=r} x[src[e]] ) @ W[r]
//
// Pipeline:
//   1. counting sort edges by key = rel*N + dst  (hist -> 3-kernel scan -> place)
//      CSR run length IS the count -> no separate count/inv pass
//   2. gather: agg_r[dst] = (1/cnt) * sum x[src]   (bf16 output, no atomics)
//   3. GEMM: out = sum_r agg_r @ W_r + bias  via mfma_f32_16x16x32_bf16
//      (fused over rels if workspace allows -> single out write, no RMW)

#define C128 128

typedef __attribute__((ext_vector_type(8))) short short8;
typedef __attribute__((ext_vector_type(4))) float f32x4;

// ---------------- counting sort ----------------

__global__ __launch_bounds__(256) void hist_kernel(const int* __restrict__ ei,
                                                   const int* __restrict__ et,
                                                   unsigned* __restrict__ cnt,
                                                   int n_edges, int n_nodes) {
    int e = blockIdx.x * 256 + threadIdx.x;
    if (e < n_edges)
        atomicAdd(&cnt[(size_t)et[e] * n_nodes + ei[n_edges + e]], 1u);
}

__global__ __launch_bounds__(256) void scan1_kernel(const unsigned* __restrict__ cnt,
                                                    unsigned* __restrict__ part, int total) {
    __shared__ unsigned s[256];
    int t = threadIdx.x;
    int base = blockIdx.x * 1024 + t * 4;
    unsigned sum = 0;
#pragma unroll
    for (int i = 0; i < 4; ++i) {
        int idx = base + i;
        if (idx < total) sum += cnt[idx];
    }
    s[t] = sum;
    __syncthreads();
    for (int d = 128; d > 0; d >>= 1) {
        if (t < d) s[t] += s[t + d];
        __syncthreads();
    }
    if (t == 0) part[blockIdx.x] = s[0];
}

__global__ __launch_bounds__(512) void scan2_kernel(unsigned* __restrict__ part, int nblk) {
    __shared__ unsigned s[512];
    int t = threadIdx.x;
    unsigned run = 0;
    for (int base = 0; base < nblk; base += 512) {
        int i = base + t;
        unsigned v = (i < nblk) ? part[i] : 0u;
        s[t] = v;
        __syncthreads();
        for (int d = 1; d < 512; d <<= 1) {
            unsigned u = (t >= d) ? s[t - d] : 0u;
            __syncthreads();
            s[t] += u;
            __syncthreads();
        }
        unsigned incl = s[t];
        if (i < nblk) part[i] = run + incl - v;  // exclusive
        unsigned tot = s[511];
        __syncthreads();
        run += tot;
    }
}

// reads cnt (cursor buffer), writes exclusive-scan into off AND back into cursor
__global__ __launch_bounds__(256) void scan3_kernel(unsigned* __restrict__ cursor,
                                                    unsigned* __restrict__ off,
                                                    const unsigned* __restrict__ part,
                                                    int total, int n_edges) {
    __shared__ unsigned s[256];
    int t = threadIdx.x;
    int base = blockIdx.x * 1024 + t * 4;
    unsigned v[4];
    unsigned tsum = 0;
#pragma unroll
    for (int i = 0; i < 4; ++i) {
        int idx = base + i;
        v[i] = (idx < total) ? cursor[idx] : 0u;
        tsum += v[i];
    }
    s[t] = tsum;
    __syncthreads();
    for (int d = 1; d < 256; d <<= 1) {
        unsigned u = (t >= d) ? s[t - d] : 0u;
        __syncthreads();
        s[t] += u;
        __syncthreads();
    }
    unsigned run = s[t] - tsum + part[blockIdx.x];
#pragma unroll
    for (int i = 0; i < 4; ++i) {
        int idx = base + i;
        if (idx < total) {
            off[idx] = run;
            cursor[idx] = run;
            run += v[i];
        }
    }
    if (blockIdx.x == 0 && t == 0) off[total] = (unsigned)n_edges;
}

__global__ __launch_bounds__(256) void place_kernel(const int* __restrict__ ei,
                                                    const int* __restrict__ et,
                                                    unsigned* __restrict__ cursor,
                                                    int* __restrict__ sorted_src,
                                                    int n_edges, int n_nodes) {
    int e = blockIdx.x * 256 + threadIdx.x;
    if (e < n_edges) {
        int key = et[e] * n_nodes + ei[n_edges + e];
        unsigned pos = atomicAdd(&cursor[key], 1u);
        sorted_src[pos] = ei[e];
    }
}

// ---------------- weight convert: WbT[r][n][k] = bf16(W[r][k][n]) ----------------

__global__ __launch_bounds__(256) void wconv_kernel(const float* __restrict__ W,
                                                    __hip_bfloat16* __restrict__ WbT,
                                                    int total) {
    int i = blockIdx.x * 256 + threadIdx.x;
    if (i < total) {
        int r = i >> 14, k = (i >> 7) & 127, n = i & 127;
        WbT[(r << 14) + (n << 7) + k] = __float2bfloat16(W[i]);
    }
}

// ---------------- gather: agg[dst] = mean of x[src] over CSR run ----------------

__global__ __launch_bounds__(256) void gather_kernel(const float* __restrict__ x,
                                                     const int* __restrict__ sorted_src,
                                                     const unsigned* __restrict__ off,
                                                     __hip_bfloat16* __restrict__ agg,
                                                     int n_nodes, int rel) {
    int wv = blockIdx.x * 4 + (threadIdx.x >> 6);
    if (wv >= n_nodes) return;
    int lane = threadIdx.x & 63;
    unsigned beg = off[(size_t)rel * n_nodes + wv];
    unsigned end = off[(size_t)rel * n_nodes + wv + 1];
    float a0 = 0.0f, a1 = 0.0f;
    for (unsigned e = beg; e < end; ++e) {
        int src = sorted_src[e];
        a0 += x[(size_t)src * C128 + lane];
        a1 += x[(size_t)src * C128 + 64 + lane];
    }
    float s = (end > beg) ? 1.0f / (float)(end - beg) : 0.0f;
    agg[(size_t)wv * C128 + lane]      = __float2bfloat16(a0 * s);
    agg[(size_t)wv * C128 + 64 + lane] = __float2bfloat16(a1 * s);
}

// ---------------- GEMM: out(64-row tile) (+)= sum_p agg_p @ W_p ----------------
// mode 0: out = acc + bias   mode 1: out += acc

#define LDK 136  // padded bf16 row stride (272 B: 16B-aligned, balanced banks)

__global__ __launch_bounds__(256) void gemm_kernel(const __hip_bfloat16* __restrict__ agg,
                                                   const __hip_bfloat16* __restrict__ WbT,
                                                   const float* __restrict__ bias,
                                                   float* __restrict__ out,
                                                   int n_nodes, int n_pass, int mode) {
    __shared__ __hip_bfloat16 sA[64][LDK];
    __shared__ __hip_bfloat16 sW[128][LDK];
    const int t = threadIdx.x;
    const int lane = t & 63, w = t >> 6;
    const int row0 = blockIdx.x * 64;

    f32x4 acc[8];
#pragma unroll
    for (int i = 0; i < 8; ++i) acc[i] = (f32x4){0.f, 0.f, 0.f, 0.f};

    for (int p = 0; p < n_pass; ++p) {
        const __hip_bfloat16* aggp = agg + (size_t)p * n_nodes * C128;
        const __hip_bfloat16* wp = WbT + ((size_t)p << 14);
        // stage W (n,k layout), 128 rows x 16 chunks of 16B
        for (int c = t; c < 128 * 16; c += 256) {
            int rn = c >> 4, ck = (c & 15) << 3;
            *reinterpret_cast<short8*>(&sW[rn][ck]) =
                *reinterpret_cast<const short8*>(&wp[(rn << 7) + ck]);
        }
        // stage A tile, 64 rows x 16 chunks
        for (int c = t; c < 64 * 16; c += 256) {
            int rr = c >> 4, ck = (c & 15) << 3;
            int gr = row0 + rr;
            short8 v = (short8){0, 0, 0, 0, 0, 0, 0, 0};
            if (gr < n_nodes)
                v = *reinterpret_cast<const short8*>(&aggp[(size_t)gr * C128 + ck]);
            *reinterpret_cast<short8*>(&sA[rr][ck]) = v;
        }
        __syncthreads();

        const int ar = w * 16 + (lane & 15);
        const int k0base = (lane >> 4) << 3;
#pragma unroll
        for (int kt = 0; kt < 4; ++kt) {
            int k0 = kt * 32 + k0base;
            short8 af = *reinterpret_cast<const short8*>(&sA[ar][k0]);
#pragma unroll
            for (int nt = 0; nt < 8; ++nt) {
                short8 bf = *reinterpret_cast<const short8*>(&sW[nt * 16 + (lane & 15)][k0]);
                acc[nt] = __builtin_amdgcn_mfma_f32_16x16x32_bf16(af, bf, acc[nt], 0, 0, 0);
            }
        }
        __syncthreads();
    }

    // epilogue: D row = 4*(lane>>4)+i, col = lane&15 (per 16x16 tile)
    const int rbase = row0 + w * 16 + ((lane >> 4) << 2);
    const int cbase = lane & 15;
#pragma unroll
    for (int nt = 0; nt < 8; ++nt) {
        int col = nt * 16 + cbase;
#pragma unroll
        for (int i = 0; i < 4; ++i) {
            int r = rbase + i;
            if (r < n_nodes) {
                size_t o = (size_t)r * C128 + col;
                if (mode == 0) out[o] = acc[nt][i] + bias[col];
                else           out[o] += acc[nt][i];
            }
        }
    }
}

// ---------------- host ----------------

static inline char* align16p(char* p) {
    return (char*)(((uintptr_t)p + 15) & ~(uintptr_t)15);
}

extern "C" void kernel_launch(void* const* d_in, const int* in_sizes, int n_in,
                              void* d_out, int out_size, void* d_ws, size_t ws_size,
                              hipStream_t stream) {
    const float* x    = (const float*)d_in[0];
    const int*   ei   = (const int*)d_in[1];   // [2][E]
    const int*   et   = (const int*)d_in[2];   // [E]
    const float* W    = (const float*)d_in[3]; // [R][128][128]
    const float* bias = (const float*)d_in[4]; // [128]
    float* out = (float*)d_out;

    const int n_nodes = in_sizes[0] / C128;
    const int n_edges = in_sizes[2];
    const int n_rel   = in_sizes[3] / (C128 * C128);
    const int RN = n_rel * n_nodes;

    // workspace layout
    char* p = (char*)d_ws;
    unsigned* off = (unsigned*)p;      p += (size_t)(RN + 1) * 4; p = align16p(p);
    unsigned* cursor = (unsigned*)p;   p += (size_t)RN * 4;       p = align16p(p);
    unsigned* part = (unsigned*)p;     p += 4096 * 4;
    int* sorted_src = (int*)p;         p += (size_t)n_edges * 4;  p = align16p(p);
    __hip_bfloat16* WbT = (__hip_bfloat16*)p; p += (size_t)n_rel * C128 * C128 * 2; p = align16p(p);
    __hip_bfloat16* agg = (__hip_bfloat16*)p;
    size_t base_used = (size_t)(p - (char*)d_ws);
    size_t agg_fused_bytes = (size_t)n_rel * n_nodes * C128 * 2;
    size_t agg_one_bytes   = (size_t)n_nodes * C128 * 2;
    bool fused = (ws_size >= base_used + agg_fused_bytes) && (agg_one_bytes > 0);

    // 1. counting sort
    hipMemsetAsync(cursor, 0, (size_t)RN * 4, stream);
    hist_kernel<<<(n_edges + 255) / 256, 256, 0, stream>>>(ei, et, cursor, n_edges, n_nodes);
    int nblk = (RN + 1023) / 1024;
    scan1_kernel<<<nblk, 256, 0, stream>>>(cursor, part, RN);
    scan2_kernel<<<1, 512, 0, stream>>>(part, nblk);
    scan3_kernel<<<nblk, 256, 0, stream>>>(cursor, off, part, RN, n_edges);
    place_kernel<<<(n_edges + 255) / 256, 256, 0, stream>>>(ei, et, cursor, sorted_src,
                                                            n_edges, n_nodes);
    // 2. weights -> bf16 transposed
    int wtot = n_rel * C128 * C128;
    wconv_kernel<<<(wtot + 255) / 256, 256, 0, stream>>>(W, WbT, wtot);

    // 3. gather + GEMM
    int gblk = (n_nodes + 3) / 4;
    int mblk = (n_nodes + 63) / 64;
    if (fused) {
        for (int r = 0; r < n_rel; ++r)
            gather_kernel<<<gblk, 256, 0, stream>>>(x, sorted_src, off,
                                                    agg + (size_t)r * n_nodes * C128,
                                                    n_nodes, r);
        gemm_kernel<<<mblk, 256, 0, stream>>>(agg, WbT, bias, out, n_nodes, n_rel, 0);
    } else {
        for (int r = 0; r < n_rel; ++r) {
            gather_kernel<<<gblk, 256, 0, stream>>>(x, sorted_src, off, agg, n_nodes, r);
            gemm_kernel<<<mblk, 256, 0, stream>>>(agg, WbT + ((size_t)r << 14), bias, out,
                                                  n_nodes, 1, r == 0 ? 0 : 1);
        }
    }
}

// Round 3
// 221.995 us; speedup vs baseline: 3.6229x; 1.2476x over previous
//
#include <hip/hip_runtime.h>
#include <hip/hip_bf16.h>

// SimpleGraphConv (RGCN-mean), aggregate-first:
//   out[n] = bias + sum_r ( mean_{e: dst=n, type=r} x[src[e]] ) @ W[r]
//
//   1. counting sort edges by key = rel*N + dst -> CSR (run length = count)
//   2. ONE gather launch: agg[key] = mean x[src]  (bf16, pre-XOR-swizzled layout)
//   3. ONE GEMM: out = sum_r agg_r @ W_r + bias   (mfma 16x16x32 bf16,
//      global_load_lds staging, swizzled ds_read -> no bank conflicts)

#define C128 128

typedef __attribute__((ext_vector_type(8))) short short8;
typedef __attribute__((ext_vector_type(4))) float f32x4;

__device__ __forceinline__ void gload_lds16(void* lds, const void* gsrc) {
    __builtin_amdgcn_global_load_lds(
        (const __attribute__((address_space(1))) unsigned int*)gsrc,
        (__attribute__((address_space(3))) unsigned int*)lds, 16, 0, 0);
}

// ---------------- counting sort ----------------

__global__ __launch_bounds__(256) void hist_kernel(const int* __restrict__ ei,
                                                   const int* __restrict__ et,
                                                   unsigned* __restrict__ cnt,
                                                   int n_edges, int n_nodes) {
    int e = blockIdx.x * 256 + threadIdx.x;
    if (e < n_edges)
        atomicAdd(&cnt[(size_t)et[e] * n_nodes + ei[n_edges + e]], 1u);
}

__global__ __launch_bounds__(256) void scan1_kernel(const unsigned* __restrict__ cnt,
                                                    unsigned* __restrict__ part, int total) {
    __shared__ unsigned s[256];
    int t = threadIdx.x;
    int base = blockIdx.x * 1024 + t * 4;
    unsigned sum = 0;
#pragma unroll
    for (int i = 0; i < 4; ++i) {
        int idx = base + i;
        if (idx < total) sum += cnt[idx];
    }
    s[t] = sum;
    __syncthreads();
    for (int d = 128; d > 0; d >>= 1) {
        if (t < d) s[t] += s[t + d];
        __syncthreads();
    }
    if (t == 0) part[blockIdx.x] = s[0];
}

__global__ __launch_bounds__(512) void scan2_kernel(unsigned* __restrict__ part, int nblk) {
    __shared__ unsigned s[512];
    int t = threadIdx.x;
    unsigned run = 0;
    for (int base = 0; base < nblk; base += 512) {
        int i = base + t;
        unsigned v = (i < nblk) ? part[i] : 0u;
        s[t] = v;
        __syncthreads();
        for (int d = 1; d < 512; d <<= 1) {
            unsigned u = (t >= d) ? s[t - d] : 0u;
            __syncthreads();
            s[t] += u;
            __syncthreads();
        }
        unsigned incl = s[t];
        if (i < nblk) part[i] = run + incl - v;  // exclusive
        unsigned tot = s[511];
        __syncthreads();
        run += tot;
    }
}

__global__ __launch_bounds__(256) void scan3_kernel(unsigned* __restrict__ cursor,
                                                    unsigned* __restrict__ off,
                                                    const unsigned* __restrict__ part,
                                                    int total, int n_edges) {
    __shared__ unsigned s[256];
    int t = threadIdx.x;
    int base = blockIdx.x * 1024 + t * 4;
    unsigned v[4];
    unsigned tsum = 0;
#pragma unroll
    for (int i = 0; i < 4; ++i) {
        int idx = base + i;
        v[i] = (idx < total) ? cursor[idx] : 0u;
        tsum += v[i];
    }
    s[t] = tsum;
    __syncthreads();
    for (int d = 1; d < 256; d <<= 1) {
        unsigned u = (t >= d) ? s[t - d] : 0u;
        __syncthreads();
        s[t] += u;
        __syncthreads();
    }
    unsigned run = s[t] - tsum + part[blockIdx.x];
#pragma unroll
    for (int i = 0; i < 4; ++i) {
        int idx = base + i;
        if (idx < total) {
            off[idx] = run;
            cursor[idx] = run;
            run += v[i];
        }
    }
    if (blockIdx.x == 0 && t == 0) off[total] = (unsigned)n_edges;
}

__global__ __launch_bounds__(256) void place_kernel(const int* __restrict__ ei,
                                                    const int* __restrict__ et,
                                                    unsigned* __restrict__ cursor,
                                                    int* __restrict__ sorted_src,
                                                    int n_edges, int n_nodes) {
    int e = blockIdx.x * 256 + threadIdx.x;
    if (e < n_edges) {
        int key = et[e] * n_nodes + ei[n_edges + e];
        unsigned pos = atomicAdd(&cursor[key], 1u);
        sorted_src[pos] = ei[e];
    }
}

// ------- weights: WbT[r][n][swz(k)] = bf16(W[r][k][n]), chunk16 ^= n&7 -------

__global__ __launch_bounds__(256) void wconv_kernel(const float* __restrict__ W,
                                                    __hip_bfloat16* __restrict__ WbT,
                                                    int total) {
    int i = blockIdx.x * 256 + threadIdx.x;
    if (i < total) {
        int r = i >> 14, k = (i >> 7) & 127, n = i & 127;
        int pos = (r << 14) + (n << 7) + ((((k >> 3) ^ (n & 7)) << 3) | (k & 7));
        WbT[pos] = __float2bfloat16(W[i]);
    }
}

// ------- gather: one wave per key (rel*N+dst); agg written pre-swizzled -------

__global__ __launch_bounds__(256) void gather_all_kernel(const float* __restrict__ x,
                                                         const int* __restrict__ sorted_src,
                                                         const unsigned* __restrict__ off,
                                                         __hip_bfloat16* __restrict__ agg,
                                                         int n_nodes, int rn) {
    int wv = blockIdx.x * 4 + (threadIdx.x >> 6);
    if (wv >= rn) return;
    int lane = threadIdx.x & 63;
    unsigned beg = off[wv];
    unsigned end = off[wv + 1];
    int node = wv % n_nodes;
    float a0 = 0.0f, a1 = 0.0f;
    for (unsigned e = beg; e < end; ++e) {
        int src = sorted_src[e];
        float2 v = *reinterpret_cast<const float2*>(&x[(size_t)src * C128 + lane * 2]);
        a0 += v.x;
        a1 += v.y;
    }
    float s = (end > beg) ? 1.0f / (float)(end - beg) : 0.0f;
    // channels (2*lane, 2*lane+1) -> chunk16 = lane>>2, swizzled by node&7
    int pos = wv * C128 + ((((lane >> 2) ^ (node & 7)) << 3) | ((lane & 3) << 1));
    __hip_bfloat162 pr;
    pr.x = __float2bfloat16(a0 * s);
    pr.y = __float2bfloat16(a1 * s);
    *reinterpret_cast<__hip_bfloat162*>(&agg[pos]) = pr;
}

// ------- GEMM: 128-row tile, 512 threads, acc held across relation passes -------
// mode 0: out = acc + bias    mode 1: out += acc

__global__ __launch_bounds__(512, 4) void gemm_kernel(const __hip_bfloat16* __restrict__ agg,
                                                      const __hip_bfloat16* __restrict__ WbT,
                                                      const float* __restrict__ bias,
                                                      float* __restrict__ out,
                                                      int n_nodes, int n_pass, int mode) {
    __shared__ __align__(16) __hip_bfloat16 sA[128 * C128];  // 32 KB, swizzled bytes
    __shared__ __align__(16) __hip_bfloat16 sW[128 * C128];  // 32 KB, swizzled bytes
    const int t = threadIdx.x;
    const int lane = t & 63, w = t >> 6;
    const int row0 = blockIdx.x * 128;
    const bool full = (row0 + 128 <= n_nodes);

    f32x4 acc[8];
#pragma unroll
    for (int i = 0; i < 8; ++i) acc[i] = (f32x4){0.f, 0.f, 0.f, 0.f};

    for (int p = 0; p < n_pass; ++p) {
        const __hip_bfloat16* aggp = agg + ((size_t)p * n_nodes + row0) * C128;
        const __hip_bfloat16* wp = WbT + ((size_t)p << 14);
        // stage W: 32 KB, 4 issues/thread (wave w covers 1 KB per issue)
#pragma unroll
        for (int i = 0; i < 4; ++i) {
            int seg = i * 8 + w;  // 0..31, 1 KB segments
            gload_lds16((char*)sW + seg * 1024 + lane * 16,
                        (const char*)wp + seg * 1024 + lane * 16);
        }
        // stage A: 32 KB (verbatim copy — swizzle already in global layout)
        if (full) {
#pragma unroll
            for (int i = 0; i < 4; ++i) {
                int seg = i * 8 + w;
                gload_lds16((char*)sA + seg * 1024 + lane * 16,
                            (const char*)aggp + seg * 1024 + lane * 16);
            }
        } else {
            for (int c = t; c < 128 * 16; c += 512) {
                int rr = c >> 4, ck = c & 15;
                short8 v = (short8){0, 0, 0, 0, 0, 0, 0, 0};
                if (row0 + rr < n_nodes)
                    v = *reinterpret_cast<const short8*>(&aggp[(rr << 7) + (ck << 3)]);
                *reinterpret_cast<short8*>(&sA[(rr << 7) + (ck << 3)]) = v;
            }
        }
        __syncthreads();

        const int ar = w * 16 + (lane & 15);
        const int akey = ar & 7;
        const int wr = lane & 15;  // row-within-16 for W tiles
#pragma unroll
        for (int kt = 0; kt < 4; ++kt) {
            int chunk = kt * 4 + (lane >> 4);  // logical 16B chunk (k = chunk*8..)
            short8 af = *reinterpret_cast<const short8*>(&sA[(ar << 7) + ((chunk ^ akey) << 3)]);
#pragma unroll
            for (int nt = 0; nt < 8; ++nt) {
                int wn = nt * 16 + wr;
                short8 bf = *reinterpret_cast<const short8*>(
                    &sW[(wn << 7) + ((chunk ^ (wn & 7)) << 3)]);
                acc[nt] = __builtin_amdgcn_mfma_f32_16x16x32_bf16(af, bf, acc[nt], 0, 0, 0);
            }
        }
        __syncthreads();
    }

    // epilogue: D row = 4*(lane>>4)+i, col = lane&15 (per 16x16 tile)
    const int rbase = row0 + w * 16 + ((lane >> 4) << 2);
    const int cbase = lane & 15;
#pragma unroll
    for (int nt = 0; nt < 8; ++nt) {
        int col = nt * 16 + cbase;
        float b = bias[col];
#pragma unroll
        for (int i = 0; i < 4; ++i) {
            int r = rbase + i;
            if (r < n_nodes) {
                size_t o = (size_t)r * C128 + col;
                if (mode == 0) out[o] = acc[nt][i] + b;
                else           out[o] += acc[nt][i];
            }
        }
    }
}

// ---------------- host ----------------

static inline char* align16p(char* p) {
    return (char*)(((uintptr_t)p + 15) & ~(uintptr_t)15);
}

extern "C" void kernel_launch(void* const* d_in, const int* in_sizes, int n_in,
                              void* d_out, int out_size, void* d_ws, size_t ws_size,
                              hipStream_t stream) {
    const float* x    = (const float*)d_in[0];
    const int*   ei   = (const int*)d_in[1];   // [2][E]
    const int*   et   = (const int*)d_in[2];   // [E]
    const float* W    = (const float*)d_in[3]; // [R][128][128]
    const float* bias = (const float*)d_in[4]; // [128]
    float* out = (float*)d_out;

    const int n_nodes = in_sizes[0] / C128;
    const int n_edges = in_sizes[2];
    const int n_rel   = in_sizes[3] / (C128 * C128);
    const int RN = n_rel * n_nodes;

    // workspace layout
    char* p = (char*)d_ws;
    unsigned* off = (unsigned*)p;      p += (size_t)(RN + 1) * 4; p = align16p(p);
    unsigned* cursor = (unsigned*)p;   p += (size_t)RN * 4;       p = align16p(p);
    unsigned* part = (unsigned*)p;     p += 4096 * 4;
    int* sorted_src = (int*)p;         p += (size_t)n_edges * 4;  p = align16p(p);
    __hip_bfloat16* WbT = (__hip_bfloat16*)p; p += (size_t)n_rel * C128 * C128 * 2; p = align16p(p);
    __hip_bfloat16* agg = (__hip_bfloat16*)p;
    size_t base_used = (size_t)(p - (char*)d_ws);
    size_t agg_fused_bytes = (size_t)RN * C128 * 2;
    bool fused = (ws_size >= base_used + agg_fused_bytes);

    // 1. counting sort
    hipMemsetAsync(cursor, 0, (size_t)RN * 4, stream);
    hist_kernel<<<(n_edges + 255) / 256, 256, 0, stream>>>(ei, et, cursor, n_edges, n_nodes);
    int nblk = (RN + 1023) / 1024;
    scan1_kernel<<<nblk, 256, 0, stream>>>(cursor, part, RN);
    scan2_kernel<<<1, 512, 0, stream>>>(part, nblk);
    scan3_kernel<<<nblk, 256, 0, stream>>>(cursor, off, part, RN, n_edges);
    place_kernel<<<(n_edges + 255) / 256, 256, 0, stream>>>(ei, et, cursor, sorted_src,
                                                            n_edges, n_nodes);
    // 2. weights -> bf16, transposed + swizzled
    int wtot = n_rel * C128 * C128;
    wconv_kernel<<<(wtot + 255) / 256, 256, 0, stream>>>(W, WbT, wtot);

    int mblk = (n_nodes + 127) / 128;
    if (fused) {
        // 3. one gather over all keys, one GEMM over all relations
        gather_all_kernel<<<(RN + 3) / 4, 256, 0, stream>>>(x, sorted_src, off, agg,
                                                            n_nodes, RN);
        gemm_kernel<<<mblk, 512, 0, stream>>>(agg, WbT, bias, out, n_nodes, n_rel, 0);
    } else {
        for (int r = 0; r < n_rel; ++r) {
            gather_all_kernel<<<(n_nodes + 3) / 4, 256, 0, stream>>>(
                x, sorted_src + 0, off + (size_t)r * n_nodes, agg, n_nodes, n_nodes);
            gemm_kernel<<<mblk, 512, 0, stream>>>(agg, WbT + ((size_t)r << 14), bias, out,
                                                  n_nodes, 1, r == 0 ? 0 : 1);
        }
    }
}

// Round 4
// 201.838 us; speedup vs baseline: 3.9847x; 1.0999x over previous
//
#include <hip/hip_runtime.h>
#include <hip/hip_bf16.h>

// SimpleGraphConv (RGCN-mean), fused aggregate-first:
//   out[n] = bias + sum_r ( mean_{e: dst=n, type=r} x[src[e]] ) @ W[r]
//
//   1. counting sort edges by key = rel*N + dst -> CSR (run length = count)
//   2. x -> bf16 (halves edge-driven gather traffic; L2/L3 resident)
//   3. ONE fused kernel: per 128-node tile, per relation:
//        gather mean x_bf16[src] rows straight into swizzled LDS A-tile,
//        stage W via global_load_lds (pre-swizzled global layout),
//        MFMA 16x16x32 bf16 with acc held across relations. No agg buffer.

#define C128 128

typedef __attribute__((ext_vector_type(8))) short short8;
typedef __attribute__((ext_vector_type(4))) float f32x4;

__device__ __forceinline__ void gload_lds16(void* lds, const void* gsrc) {
    __builtin_amdgcn_global_load_lds(
        (const __attribute__((address_space(1))) unsigned int*)gsrc,
        (__attribute__((address_space(3))) unsigned int*)lds, 16, 0, 0);
}

__device__ __forceinline__ float bf16_bits_to_f32(unsigned short u) {
    union { unsigned int i; float f; } c;
    c.i = ((unsigned int)u) << 16;
    return c.f;
}

// ---------------- counting sort ----------------

__global__ __launch_bounds__(256) void hist_kernel(const int* __restrict__ ei,
                                                   const int* __restrict__ et,
                                                   unsigned* __restrict__ cnt,
                                                   int n_edges, int n_nodes) {
    int e = blockIdx.x * 256 + threadIdx.x;
    if (e < n_edges)
        atomicAdd(&cnt[(size_t)et[e] * n_nodes + ei[n_edges + e]], 1u);
}

__global__ __launch_bounds__(256) void scan1_kernel(const unsigned* __restrict__ cnt,
                                                    unsigned* __restrict__ part, int total) {
    __shared__ unsigned s[256];
    int t = threadIdx.x;
    int base = blockIdx.x * 1024 + t * 4;
    unsigned sum = 0;
#pragma unroll
    for (int i = 0; i < 4; ++i) {
        int idx = base + i;
        if (idx < total) sum += cnt[idx];
    }
    s[t] = sum;
    __syncthreads();
    for (int d = 128; d > 0; d >>= 1) {
        if (t < d) s[t] += s[t + d];
        __syncthreads();
    }
    if (t == 0) part[blockIdx.x] = s[0];
}

__global__ __launch_bounds__(512) void scan2_kernel(unsigned* __restrict__ part, int nblk) {
    __shared__ unsigned s[512];
    int t = threadIdx.x;
    unsigned run = 0;
    for (int base = 0; base < nblk; base += 512) {
        int i = base + t;
        unsigned v = (i < nblk) ? part[i] : 0u;
        s[t] = v;
        __syncthreads();
        for (int d = 1; d < 512; d <<= 1) {
            unsigned u = (t >= d) ? s[t - d] : 0u;
            __syncthreads();
            s[t] += u;
            __syncthreads();
        }
        unsigned incl = s[t];
        if (i < nblk) part[i] = run + incl - v;  // exclusive
        unsigned tot = s[511];
        __syncthreads();
        run += tot;
    }
}

__global__ __launch_bounds__(256) void scan3_kernel(unsigned* __restrict__ cursor,
                                                    unsigned* __restrict__ off,
                                                    const unsigned* __restrict__ part,
                                                    int total, int n_edges) {
    __shared__ unsigned s[256];
    int t = threadIdx.x;
    int base = blockIdx.x * 1024 + t * 4;
    unsigned v[4];
    unsigned tsum = 0;
#pragma unroll
    for (int i = 0; i < 4; ++i) {
        int idx = base + i;
        v[i] = (idx < total) ? cursor[idx] : 0u;
        tsum += v[i];
    }
    s[t] = tsum;
    __syncthreads();
    for (int d = 1; d < 256; d <<= 1) {
        unsigned u = (t >= d) ? s[t - d] : 0u;
        __syncthreads();
        s[t] += u;
        __syncthreads();
    }
    unsigned run = s[t] - tsum + part[blockIdx.x];
#pragma unroll
    for (int i = 0; i < 4; ++i) {
        int idx = base + i;
        if (idx < total) {
            off[idx] = run;
            cursor[idx] = run;
            run += v[i];
        }
    }
    if (blockIdx.x == 0 && t == 0) off[total] = (unsigned)n_edges;
}

__global__ __launch_bounds__(256) void place_kernel(const int* __restrict__ ei,
                                                    const int* __restrict__ et,
                                                    unsigned* __restrict__ cursor,
                                                    int* __restrict__ sorted_src,
                                                    int n_edges, int n_nodes) {
    int e = blockIdx.x * 256 + threadIdx.x;
    if (e < n_edges) {
        int key = et[e] * n_nodes + ei[n_edges + e];
        unsigned pos = atomicAdd(&cursor[key], 1u);
        sorted_src[pos] = ei[e];
    }
}

// ------- weights: WbT[r][n][swz(k)] = bf16(W[r][k][n]), chunk16 ^= n&7 -------

__global__ __launch_bounds__(256) void wconv_kernel(const float* __restrict__ W,
                                                    __hip_bfloat16* __restrict__ WbT,
                                                    int total) {
    int i = blockIdx.x * 256 + threadIdx.x;
    if (i < total) {
        int r = i >> 14, k = (i >> 7) & 127, n = i & 127;
        int pos = (r << 14) + (n << 7) + ((((k >> 3) ^ (n & 7)) << 3) | (k & 7));
        WbT[pos] = __float2bfloat16(W[i]);
    }
}

// ------- x -> bf16 (plain [N][128] layout) -------

__global__ __launch_bounds__(256) void xconv_kernel(const float* __restrict__ x,
                                                    __hip_bfloat16* __restrict__ xb,
                                                    int total8) {
    int i = blockIdx.x * 256 + threadIdx.x;
    if (i >= total8) return;
    const float4* src = reinterpret_cast<const float4*>(x + (size_t)i * 8);
    float4 v0 = src[0], v1 = src[1];
    short8 o;
    o[0] = (short)__bfloat16_as_ushort(__float2bfloat16(v0.x));
    o[1] = (short)__bfloat16_as_ushort(__float2bfloat16(v0.y));
    o[2] = (short)__bfloat16_as_ushort(__float2bfloat16(v0.z));
    o[3] = (short)__bfloat16_as_ushort(__float2bfloat16(v0.w));
    o[4] = (short)__bfloat16_as_ushort(__float2bfloat16(v1.x));
    o[5] = (short)__bfloat16_as_ushort(__float2bfloat16(v1.y));
    o[6] = (short)__bfloat16_as_ushort(__float2bfloat16(v1.z));
    o[7] = (short)__bfloat16_as_ushort(__float2bfloat16(v1.w));
    *reinterpret_cast<short8*>(reinterpret_cast<unsigned short*>(xb) + (size_t)i * 8) = o;
}

// ------- fused gather+GEMM: 128-node tile, 512 threads, acc across relations -------

__global__ __launch_bounds__(512, 4) void fused_kernel(const __hip_bfloat16* __restrict__ xb,
                                                       const int* __restrict__ sorted_src,
                                                       const unsigned* __restrict__ off,
                                                       const __hip_bfloat16* __restrict__ WbT,
                                                       const float* __restrict__ bias,
                                                       float* __restrict__ out,
                                                       int n_nodes, int n_rel) {
    __shared__ __align__(16) __hip_bfloat16 sA[128 * C128];  // 32 KB, swizzled
    __shared__ __align__(16) __hip_bfloat16 sW[128 * C128];  // 32 KB, swizzled
    const int t = threadIdx.x;
    const int lane = t & 63, w = t >> 6;
    const int g = lane >> 4;        // key sub-group 0..3
    const int c = lane & 15;        // 16B chunk 0..15
    const int row0 = blockIdx.x * 128;

    f32x4 acc[8];
#pragma unroll
    for (int i = 0; i < 8; ++i) acc[i] = (f32x4){0.f, 0.f, 0.f, 0.f};

    for (int p = 0; p < n_rel; ++p) {
        // issue async W staging first (overlaps with gather below)
        const __hip_bfloat16* wp = WbT + ((size_t)p << 14);
#pragma unroll
        for (int i = 0; i < 4; ++i) {
            int seg = i * 8 + w;  // 1 KB segments
            gload_lds16((char*)sW + seg * 1024 + lane * 16,
                        (const char*)wp + seg * 1024 + lane * 16);
        }
        // gather: 8 waves x 4 keys/iter x 4 iters = 128 rows; 16 lanes per key
        const unsigned* offp = off + (size_t)p * n_nodes;
#pragma unroll
        for (int it = 0; it < 4; ++it) {
            int rr = w * 16 + it * 4 + g;  // row within tile
            int node = row0 + rr;
            unsigned beg = 0, end = 0;
            if (node < n_nodes) {
                beg = offp[node];
                end = offp[node + 1];
            }
            float a[8];
#pragma unroll
            for (int j = 0; j < 8; ++j) a[j] = 0.f;
            for (unsigned e = beg; e < end; ++e) {
                int src = sorted_src[e];
                short8 v = *reinterpret_cast<const short8*>(
                    reinterpret_cast<const unsigned short*>(xb) + ((size_t)src << 7) + c * 8);
#pragma unroll
                for (int j = 0; j < 8; ++j) a[j] += bf16_bits_to_f32((unsigned short)v[j]);
            }
            float s = (end > beg) ? 1.0f / (float)(end - beg) : 0.0f;
            short8 o;
#pragma unroll
            for (int j = 0; j < 8; ++j)
                o[j] = (short)__bfloat16_as_ushort(__float2bfloat16(a[j] * s));
            *reinterpret_cast<short8*>(&sA[(rr << 7) + (((c ^ (rr & 7))) << 3)]) = o;
        }
        __syncthreads();  // drains vmcnt (W) + lgkmcnt (A writes)

        const int ar = w * 16 + (lane & 15);
        const int akey = ar & 7;
        const int wr = lane & 15;
#pragma unroll
        for (int kt = 0; kt < 4; ++kt) {
            int chunk = kt * 4 + (lane >> 4);
            short8 af = *reinterpret_cast<const short8*>(&sA[(ar << 7) + ((chunk ^ akey) << 3)]);
#pragma unroll
            for (int nt = 0; nt < 8; ++nt) {
                int wn = nt * 16 + wr;
                short8 bf = *reinterpret_cast<const short8*>(
                    &sW[(wn << 7) + ((chunk ^ (wn & 7)) << 3)]);
                acc[nt] = __builtin_amdgcn_mfma_f32_16x16x32_bf16(af, bf, acc[nt], 0, 0, 0);
            }
        }
        __syncthreads();
    }

    // epilogue: D row = 4*(lane>>4)+i, col = lane&15 (per 16x16 tile)
    const int rbase = row0 + w * 16 + ((lane >> 4) << 2);
    const int cbase = lane & 15;
#pragma unroll
    for (int nt = 0; nt < 8; ++nt) {
        int col = nt * 16 + cbase;
        float b = bias[col];
#pragma unroll
        for (int i = 0; i < 4; ++i) {
            int r = rbase + i;
            if (r < n_nodes)
                out[(size_t)r * C128 + col] = acc[nt][i] + b;
        }
    }
}

// ---------------- host ----------------

static inline char* align16p(char* p) {
    return (char*)(((uintptr_t)p + 15) & ~(uintptr_t)15);
}

extern "C" void kernel_launch(void* const* d_in, const int* in_sizes, int n_in,
                              void* d_out, int out_size, void* d_ws, size_t ws_size,
                              hipStream_t stream) {
    const float* x    = (const float*)d_in[0];
    const int*   ei   = (const int*)d_in[1];   // [2][E]
    const int*   et   = (const int*)d_in[2];   // [E]
    const float* W    = (const float*)d_in[3]; // [R][128][128]
    const float* bias = (const float*)d_in[4]; // [128]
    float* out = (float*)d_out;

    const int n_nodes = in_sizes[0] / C128;
    const int n_edges = in_sizes[2];
    const int n_rel   = in_sizes[3] / (C128 * C128);
    const int RN = n_rel * n_nodes;

    // workspace: off | cursor | part | sorted_src | WbT | xb   (~20 MB)
    char* p = (char*)d_ws;
    unsigned* off = (unsigned*)p;      p += (size_t)(RN + 1) * 4; p = align16p(p);
    unsigned* cursor = (unsigned*)p;   p += (size_t)RN * 4;       p = align16p(p);
    unsigned* part = (unsigned*)p;     p += 4096 * 4;
    int* sorted_src = (int*)p;         p += (size_t)n_edges * 4;  p = align16p(p);
    __hip_bfloat16* WbT = (__hip_bfloat16*)p; p += (size_t)n_rel * C128 * C128 * 2; p = align16p(p);
    __hip_bfloat16* xb = (__hip_bfloat16*)p;

    // 1. counting sort
    hipMemsetAsync(cursor, 0, (size_t)RN * 4, stream);
    hist_kernel<<<(n_edges + 255) / 256, 256, 0, stream>>>(ei, et, cursor, n_edges, n_nodes);
    int nblk = (RN + 1023) / 1024;
    scan1_kernel<<<nblk, 256, 0, stream>>>(cursor, part, RN);
    scan2_kernel<<<1, 512, 0, stream>>>(part, nblk);
    scan3_kernel<<<nblk, 256, 0, stream>>>(cursor, off, part, RN, n_edges);
    place_kernel<<<(n_edges + 255) / 256, 256, 0, stream>>>(ei, et, cursor, sorted_src,
                                                            n_edges, n_nodes);
    // 2. conversions (independent of sort; scheduler can overlap-issue)
    int wtot = n_rel * C128 * C128;
    wconv_kernel<<<(wtot + 255) / 256, 256, 0, stream>>>(W, WbT, wtot);
    int xt8 = n_nodes * (C128 / 8);
    xconv_kernel<<<(xt8 + 255) / 256, 256, 0, stream>>>(x, xb, xt8);

    // 3. fused gather + GEMM
    int mblk = (n_nodes + 127) / 128;
    fused_kernel<<<mblk, 512, 0, stream>>>(xb, sorted_src, off, WbT, bias, out,
                                           n_nodes, n_rel);
}